// Round 8
// baseline (387.108 us; speedup 1.0000x reference)
//
#include <hip/hip_runtime.h>
#include <hip/hip_bf16.h>

// NonLocalBlock: B=8, C=512, CI=256, H=W=56, N=3136.
// Round-8: attn z-split 4 (800 blocks, better CU-slot balance), 4-way
// combine, bn_stats 784 blocks, zero_stats folded into detect kernel,
// g-frag hoist over the Ps roundtrip. gemm128 & layouts unchanged (r7
// passed, 383 us, absmax 0.031).

typedef unsigned short u16;
typedef unsigned int u32;
typedef __attribute__((ext_vector_type(8))) short short8;   // 8 bf16
typedef __attribute__((ext_vector_type(4))) float floatx4;

#define B_   8
#define C_   512
#define CI_  256
#define N_   3136
#define BN_  25088   // B_*N_

__device__ __forceinline__ u16 f2b(float f) {
    return __builtin_bit_cast(u16, __float2bfloat16(f));
}
__device__ __forceinline__ float b2f(u16 u) {
    return __bfloat162float(__builtin_bit_cast(__hip_bfloat16, u));
}
__device__ __forceinline__ floatx4 mfma16(short8 a, short8 b, floatx4 c) {
    return __builtin_amdgcn_mfma_f32_16x16x32_bf16(a, b, c, 0, 0, 0);
}
// async global->LDS DMA, 16 B/lane; LDS dest = wave-uniform base + lane*16,
// source address fully per-lane (gather).
__device__ __forceinline__ void gload_lds16(const u16* g, u16* l) {
    __builtin_amdgcn_global_load_lds(
        (const __attribute__((address_space(1))) u32*)g,
        (__attribute__((address_space(3))) u32*)l, 16, 0, 0);
}

// ---------------------------------------------------------------------------
// Runtime dtype detection + stats zeroing (fused prologue, 1 block).
// ---------------------------------------------------------------------------
__global__ void detect_dtype(const u32* __restrict__ xw, int* __restrict__ flag,
                             float* __restrict__ stats)
{
    __shared__ int cnt;
    if (threadIdx.x == 0) cnt = 0;
    __syncthreads();
    int c = 0;
    for (int i = 0; i < 16; ++i) {
        u32 w = xw[threadIdx.x * 16 + i];
        u32 e = (w >> 7) & 0xFF;
        c += (e >= 118 && e <= 130) ? 1 : 0;
    }
    atomicAdd(&cnt, c);
    stats[threadIdx.x] = 0.f;
    stats[threadIdx.x + 256] = 0.f;
    stats[threadIdx.x + 512] = 0.f;
    stats[threadIdx.x + 768] = 0.f;
    __syncthreads();
    if (threadIdx.x == 0) *flag = (2 * cnt > 4096) ? 1 : 0;
}

// ---------------------------------------------------------------------------
// Convert the 10 parameter arrays into canonical bf16, flag-branched.
// ---------------------------------------------------------------------------
__global__ __launch_bounds__(256) void convert_params(
    const void* tw, const void* tb, const void* pw, const void* pb,
    const void* gw, const void* gbi, const void* ww, const void* wb,
    const void* gamma, const void* beta,
    u16* __restrict__ dst, const int* __restrict__ flag)
{
    const void* srcs[10] = {tw, tb, pw, pb, gw, gbi, ww, wb, gamma, beta};
    const int ns[10] = {131072, 256, 131072, 256, 131072, 256, 131072, 512, 512, 512};
    int seg = blockIdx.y;
    int off = 0;
    for (int s = 0; s < 10; ++s) { if (s == seg) break; off += ns[s]; }
    const void* src = srcs[seg];
    int n = ns[seg];
    int i0 = (blockIdx.x * 256 + threadIdx.x) * 8;
    if (i0 >= n) return;
    const int fl = *flag;
    u16* d = dst + off;
    for (int k = 0; k < 8; ++k) {
        int i = i0 + k;
        if (i < n)
            d[i] = fl ? ((const u16*)src)[i] : f2b(((const float*)src)[i]);
    }
}

// ---------------------------------------------------------------------------
// x ingest + transpose: x [b,C,N] (fp32 or bf16) -> xT [b,N,C] bf16.
// ---------------------------------------------------------------------------
__global__ __launch_bounds__(256) void transpose_x(
    const void* __restrict__ in, u16* __restrict__ out,
    const int* __restrict__ flag)
{
    __shared__ u16 tile[64][68];
    const int fl = *flag;
    const int t = threadIdx.x;
    const long base = (long)blockIdx.z * (long)C_ * (long)N_;
    const int c0 = blockIdx.x * 64, r0 = blockIdx.y * 64;
    const int lr = t >> 3;
    const int lc = (t & 7) * 8;
#pragma unroll
    for (int j = 0; j < 2; ++j) {
        int rr = lr + 32 * j;
        long eoff = base + (long)(r0 + rr) * N_ + c0 + lc;
        u16 v[8] __attribute__((aligned(16)));
        if (fl) {
            const u16* pi = (const u16*)in + eoff;
            *(uint64_t*)&v[0] = *(const uint64_t*)pi;
            *(uint64_t*)&v[4] = *(const uint64_t*)(pi + 4);
        } else {
            const float* pi = (const float*)in + eoff;
            floatx4 a = *(const floatx4*)pi;
            floatx4 b4 = *(const floatx4*)(pi + 4);
#pragma unroll
            for (int k = 0; k < 4; ++k) { v[k] = f2b(a[k]); v[4 + k] = f2b(b4[k]); }
        }
        *(uint64_t*)&tile[rr][lc] = *(const uint64_t*)&v[0];
        *(uint64_t*)&tile[rr][lc + 4] = *(const uint64_t*)&v[4];
    }
    __syncthreads();
#pragma unroll
    for (int j = 0; j < 2; ++j) {
        int oc = lr + 32 * j;
        int ob = (t & 7) * 8;
        u16 vals[8] __attribute__((aligned(16)));
#pragma unroll
        for (int k = 0; k < 8; ++k) vals[k] = tile[ob + k][oc];
        u16* po = out + (long)blockIdx.z * N_ * C_ + (long)(c0 + oc) * C_ + r0 + ob;
        *(uint64_t*)po = *(const uint64_t*)vals;
        *(uint64_t*)(po + 4) = *(const uint64_t*)(vals + 4);
    }
}

// ---------------------------------------------------------------------------
// bf16 64x64 tile transpose: in [z][R][Cc] -> out [z][Cc][R]
// ---------------------------------------------------------------------------
__global__ __launch_bounds__(256) void transpose64(
    const u16* __restrict__ in, u16* __restrict__ out, int R, int Cc)
{
    __shared__ u16 tile[64][68];
    const int t = threadIdx.x;
    const long base = (long)blockIdx.z * (long)R * (long)Cc;
    const int c0 = blockIdx.x * 64, r0 = blockIdx.y * 64;
    const int lr = t >> 3;
    const int lc = (t & 7) * 8;
#pragma unroll
    for (int j = 0; j < 2; ++j) {
        int rr = lr + 32 * j;
        const u16* pi = in + base + (long)(r0 + rr) * Cc + c0 + lc;
        *(uint64_t*)&tile[rr][lc] = *(const uint64_t*)pi;
        *(uint64_t*)&tile[rr][lc + 4] = *(const uint64_t*)(pi + 4);
    }
    __syncthreads();
#pragma unroll
    for (int j = 0; j < 2; ++j) {
        int oc = lr + 32 * j;
        int ob = (t & 7) * 8;
        u16 vals[8] __attribute__((aligned(16)));
#pragma unroll
        for (int k = 0; k < 8; ++k) vals[k] = tile[ob + k][oc];
        u16* po = out + base + (long)(c0 + oc) * R + r0 + ob;
        *(uint64_t*)po = *(const uint64_t*)vals;
        *(uint64_t*)(po + 4) = *(const uint64_t*)(vals + 4);
    }
}

// ---------------------------------------------------------------------------
// gemm128: Out[m][n] = sum_k A[m][k]*Bt[n][k] + bias[n], all bf16.
// 128x128 tile, BK=32, fragment-order DMA, dbuf. blockIdx.z selects the
// weight set / output slab (fused projections).
// ---------------------------------------------------------------------------
template<int K>
__global__ __launch_bounds__(256, 3) void gemm128(
    const u16* __restrict__ A,
    const u16* __restrict__ BtBase,
    const u16* __restrict__ biasBase,
    u16* __restrict__ OutBase,
    int ncols, long bstride, long ostride)
{
    __shared__ __attribute__((aligned(16))) u16 Asf[2][8][64][8];
    __shared__ __attribute__((aligned(16))) u16 Bsf[2][8][64][8];

    const int t = threadIdx.x;
    const int wave = t >> 6, lane = t & 63;
    const int q = lane >> 4, lx = lane & 15;
    const int m0 = blockIdx.x * 128;
    const int n0 = blockIdx.y * 128;
    const u16* Bt = BtBase + (long)blockIdx.z * bstride;
    const u16* bias = biasBase + (long)blockIdx.z * bstride;
    u16* Out = OutBase + (long)blockIdx.z * ostride;

    floatx4 zero4 = {0.f, 0.f, 0.f, 0.f};
    floatx4 acc[4][4];
#pragma unroll
    for (int i = 0; i < 4; ++i)
#pragma unroll
        for (int j = 0; j < 4; ++j) acc[i][j] = zero4;

    auto stage = [&](int buf, int k0) {
#pragma unroll
        for (int i = 0; i < 2; ++i) {
            int rg = wave * 2 + i;
            gload_lds16(A + (long)(m0 + rg * 16 + lx) * K + k0 + q * 8,
                        &Asf[buf][rg][0][0]);
            gload_lds16(Bt + (long)(n0 + rg * 16 + lx) * K + k0 + q * 8,
                        &Bsf[buf][rg][0][0]);
        }
    };

    stage(0, 0);
    const int rg0 = (wave >> 1) * 4, cg0 = (wave & 1) * 4;
    const int NS = K / 32;
    for (int s = 0; s < NS; ++s) {
        const int buf = s & 1;
        __syncthreads();
        if (s + 1 < NS) stage(buf ^ 1, (s + 1) * 32);
        short8 af[4], bfr[4];
#pragma unroll
        for (int i = 0; i < 4; ++i)
            af[i] = *(const short8*)&Asf[buf][rg0 + i][lane][0];
#pragma unroll
        for (int j = 0; j < 4; ++j)
            bfr[j] = *(const short8*)&Bsf[buf][cg0 + j][lane][0];
#pragma unroll
        for (int i = 0; i < 4; ++i)
#pragma unroll
            for (int j = 0; j < 4; ++j)
                acc[i][j] = mfma16(af[i], bfr[j], acc[i][j]);
    }

    const int wr = (wave >> 1) * 64, wc = (wave & 1) * 64;
#pragma unroll
    for (int j = 0; j < 4; ++j) {
        int col = n0 + wc + j * 16 + lx;
        float bv = b2f(bias[col]);
#pragma unroll
        for (int i = 0; i < 4; ++i) {
#pragma unroll
            for (int r = 0; r < 4; ++r) {
                int row = m0 + wr + i * 16 + q * 4 + r;
                Out[(long)row * ncols + col] = f2b(acc[i][j][r] + bv);
            }
        }
    }
}

// ---------------------------------------------------------------------------
// Fused attention v4.2: r7 structure, z-split 4 (splits 800/800/800/736),
// hoisted g-frags across the Ps roundtrip wait.
// grid = (25, B, 4), block = 256.  ypart[z] are separate slabs.
// ---------------------------------------------------------------------------
__global__ __launch_bounds__(256, 2) void attn(
    const u16* __restrict__ theta,   // [B][N][CI]
    const u16* __restrict__ phi,     // [B][N][CI]
    const u16* __restrict__ gT,      // [B][CI][N]
    u16* __restrict__ yp0, u16* __restrict__ yp1,
    u16* __restrict__ yp2, u16* __restrict__ yp3,
    float* __restrict__ lpart)       // [4][B][N] row exp-sums
{
    __shared__ __attribute__((aligned(16))) u16 psf[2][8][2][64][8];
    __shared__ __attribute__((aligned(16))) u16 gsf[2][16][64][8];
    __shared__ __attribute__((aligned(16))) u16 Ps[4][32][40];

    const int t = threadIdx.x;
    const int wave = t >> 6, lane = t & 63;
    const int q = lane >> 4, lx = lane & 15;
    const int b = blockIdx.y;
    const int z = blockIdx.z;
    const int n0w = blockIdx.x * 128 + wave * 32;
    const bool valid = n0w < N_;
    const u16* thb = theta + (long)b * N_ * CI_;
    const u16* phb = phi + (long)b * N_ * CI_;
    const u16* gb = gT + (long)b * CI_ * N_;

    short8 tf[2][8];
#pragma unroll
    for (int h = 0; h < 2; ++h) {
        int trow = n0w + h * 16 + lx;
        if (trow >= N_) trow = N_ - 1;
#pragma unroll
        for (int kk = 0; kk < 8; ++kk)
            tf[h][kk] = *(const short8*)(thb + (long)trow * CI_ + kk * 32 + q * 8);
    }

    floatx4 zero4 = {0.f, 0.f, 0.f, 0.f};
    floatx4 yacc[2][16];
#pragma unroll
    for (int h = 0; h < 2; ++h)
#pragma unroll
        for (int i = 0; i < 16; ++i) yacc[h][i] = zero4;
    floatx4 lacc[2] = {zero4, zero4};
    const short8 ones = {0x3F80, 0x3F80, 0x3F80, 0x3F80,
                         0x3F80, 0x3F80, 0x3F80, 0x3F80};

    const int mbeg = z * 800;
    const int mend = (z == 3) ? N_ : mbeg + 800;

    auto stage = [&](int buf, int m0) {
#pragma unroll
        for (int i = 0; i < 2; ++i) {
            int kc = wave * 2 + i;
#pragma unroll
            for (int h = 0; h < 2; ++h)
                gload_lds16(phb + (long)(m0 + h * 16 + lx) * CI_ + kc * 32 + q * 8,
                            &psf[buf][kc][h][0][0]);
        }
#pragma unroll
        for (int j4 = 0; j4 < 4; ++j4) {
            int ct = wave * 4 + j4;
            gload_lds16(gb + (long)(ct * 16 + lx) * N_ + m0 + q * 8,
                        &gsf[buf][ct][0][0]);
        }
    };

    stage(0, mbeg);
    const int NSTEP = (mend - mbeg) / 32;    // 25 or 23
    for (int s = 0; s < NSTEP; ++s) {
        const int buf = s & 1;
        __syncthreads();
        if (s + 1 < NSTEP) stage(buf ^ 1, mbeg + (s + 1) * 32);

        // ---- S = theta . phi^T ----
        floatx4 sacc[2][2];
        sacc[0][0] = zero4; sacc[0][1] = zero4;
        sacc[1][0] = zero4; sacc[1][1] = zero4;
#pragma unroll
        for (int kk = 0; kk < 8; ++kk) {
            short8 bf0 = *(const short8*)&psf[buf][kk][0][lane][0];
            short8 bf1 = *(const short8*)&psf[buf][kk][1][lane][0];
            sacc[0][0] = mfma16(tf[0][kk], bf0, sacc[0][0]);
            sacc[1][0] = mfma16(tf[1][kk], bf0, sacc[1][0]);
            sacc[0][1] = mfma16(tf[0][kk], bf1, sacc[0][1]);
            sacc[1][1] = mfma16(tf[1][kk], bf1, sacc[1][1]);
        }

        // ---- exp + pack P to A-layout via per-wave LDS ----
#pragma unroll
        for (int h = 0; h < 2; ++h)
#pragma unroll
            for (int mh = 0; mh < 2; ++mh)
#pragma unroll
                for (int r = 0; r < 4; ++r) {
                    float e = __expf(fminf(sacc[h][mh][r], 60.f));
                    Ps[wave][h * 16 + q * 4 + r][mh * 16 + lx] = f2b(e);
                }
        // hoist 4 g-frags (independent of Ps) to fill the roundtrip wait
        short8 gpre[4];
#pragma unroll
        for (int j = 0; j < 4; ++j)
            gpre[j] = *(const short8*)&gsf[buf][j][lane][0];
        __builtin_amdgcn_wave_barrier();
        short8 pA0 = *(const short8*)&Ps[wave][lx][q * 8];
        short8 pA1 = *(const short8*)&Ps[wave][16 + lx][q * 8];
        __builtin_amdgcn_wave_barrier();

        // ---- PV ----
#pragma unroll
        for (int j = 0; j < 4; ++j) {
            yacc[0][j] = mfma16(pA0, gpre[j], yacc[0][j]);
            yacc[1][j] = mfma16(pA1, gpre[j], yacc[1][j]);
        }
#pragma unroll
        for (int ct = 4; ct < 16; ++ct) {
            short8 gf = *(const short8*)&gsf[buf][ct][lane][0];
            yacc[0][ct] = mfma16(pA0, gf, yacc[0][ct]);
            yacc[1][ct] = mfma16(pA1, gf, yacc[1][ct]);
        }
        lacc[0] = mfma16(pA0, ones, lacc[0]);
        lacc[1] = mfma16(pA1, ones, lacc[1]);
    }

    if (valid) {
        u16* ypz = (z == 0) ? yp0 : (z == 1) ? yp1 : (z == 2) ? yp2 : yp3;
        u16* yb = ypz + (long)b * N_ * CI_;
#pragma unroll
        for (int h = 0; h < 2; ++h)
#pragma unroll
            for (int ct = 0; ct < 16; ++ct)
#pragma unroll
                for (int r = 0; r < 4; ++r)
                    yb[(long)(n0w + h * 16 + q * 4 + r) * CI_ + ct * 16 + lx] =
                        f2b(yacc[h][ct][r]);
        if (lx == 0) {
#pragma unroll
            for (int h = 0; h < 2; ++h)
#pragma unroll
                for (int r = 0; r < 4; ++r)
                    lpart[(long)z * BN_ + (long)b * N_ + n0w + h * 16 + q * 4 + r] =
                        lacc[h][r];
        }
    }
}

// ---------------------------------------------------------------------------
// y = (y0+y1+y2+y3) / (l0+l1+l2+l3);  grid = BN_*32/256 = 3136 blocks.
// y aliases yp2's slab: same-index read-then-write, safe per thread.
// ---------------------------------------------------------------------------
__global__ __launch_bounds__(256) void attn_combine(
    const u16* __restrict__ yp0, const u16* __restrict__ yp1,
    const u16* __restrict__ yp2, const u16* __restrict__ yp3,
    const float* __restrict__ lpart, u16* __restrict__ y)
{
    long tt = (long)blockIdx.x * 256 + threadIdx.x;
    long row = tt >> 5;
    int cb = (int)(tt & 31) * 8;
    float l = lpart[row] + lpart[BN_ + row] + lpart[2 * BN_ + row]
            + lpart[3 * BN_ + row];
    float rl = 1.0f / l;
    long off = row * CI_ + cb;
    short8 v0 = *(const short8*)(yp0 + off);
    short8 v1 = *(const short8*)(yp1 + off);
    short8 v2 = *(const short8*)(yp2 + off);
    short8 v3 = *(const short8*)(yp3 + off);
    u16 ov[8] __attribute__((aligned(16)));
#pragma unroll
    for (int j = 0; j < 8; ++j)
        ov[j] = f2b((b2f(((const u16*)&v0)[j]) + b2f(((const u16*)&v1)[j]) +
                     b2f(((const u16*)&v2)[j]) + b2f(((const u16*)&v3)[j])) * rl);
    *(short8*)(y + off) = *(const short8*)ov;
}

// ---------------------------------------------------------------------------
// BN stats over bf16 wy [b,N,C]: 784 blocks x 32 rows, partials + atomics.
// ---------------------------------------------------------------------------
__global__ __launch_bounds__(256) void bn_stats(
    const u16* __restrict__ wy, float* __restrict__ stats)
{
    const int t = threadIdx.x;
    const long row0 = (long)blockIdx.x * 32;
    float s0 = 0.f, s1 = 0.f, q0 = 0.f, q1 = 0.f;
    for (int r = 0; r < 32; ++r) {
        const u16* p = wy + (row0 + r) * C_;
        float a = b2f(p[t]), b = b2f(p[t + 256]);
        s0 += a; q0 += a * a;
        s1 += b; q1 += b * b;
    }
    atomicAdd(&stats[t], s0);
    atomicAdd(&stats[t + 256], s1);
    atomicAdd(&stats[C_ + t], q0);
    atomicAdd(&stats[C_ + t + 256], q1);
}

// ---------------------------------------------------------------------------
// out[b][c][n] = (wy[b][n][c]-mean)*rstd*gamma + beta + x[b][c][n]
// ---------------------------------------------------------------------------
__global__ __launch_bounds__(256) void bn_apply(
    const u16* __restrict__ wy, const void* __restrict__ xv,
    const u16* __restrict__ gamma, const u16* __restrict__ beta,
    const float* __restrict__ stats, void* __restrict__ outv,
    const int* __restrict__ flag)
{
    __shared__ float tile[64][65];
    const int fl = *flag;
    const int t = threadIdx.x;
    const int nb0 = blockIdx.x * 64;
    const int c0 = blockIdx.y * 64;
    const int b = blockIdx.z;
#pragma unroll
    for (int j = 0; j < 4; ++j) {
        int row = (t >> 4) + 16 * j;
        int col = (t & 15) * 4;
        const u16* p = wy + ((long)b * N_ + nb0 + row) * C_ + c0 + col;
        u16 lv[4] __attribute__((aligned(8)));
        *(uint64_t*)lv = *(const uint64_t*)p;
#pragma unroll
        for (int k = 0; k < 4; ++k) tile[row][col + k] = b2f(lv[k]);
    }
    __syncthreads();
    const float inv = 1.0f / (float)BN_;
#pragma unroll
    for (int it = 0; it < 8; ++it) {
        int oc = (t >> 5) + 8 * it;
        int on = (t & 31) * 2;
        int c = c0 + oc;
        float mean = stats[c] * inv;
        float var = stats[C_ + c] * inv - mean * mean;
        float rstd = rsqrtf(var + 1e-5f);
        float sc = b2f(gamma[c]) * rstd;
        float sh = b2f(beta[c]) - mean * sc;
        long base = ((long)b * C_ + c) * N_ + nb0 + on;
        float v0 = tile[on][oc] * sc + sh;
        float v1 = tile[on + 1][oc] * sc + sh;
        if (fl) {
            v0 += b2f(((const u16*)xv)[base]);
            v1 += b2f(((const u16*)xv)[base + 1]);
            ((u16*)outv)[base] = f2b(v0);
            ((u16*)outv)[base + 1] = f2b(v1);
        } else {
            v0 += ((const float*)xv)[base];
            v1 += ((const float*)xv)[base + 1];
            ((float*)outv)[base] = v0;
            ((float*)outv)[base + 1] = v1;
        }
    }
}

// ---------------------------------------------------------------------------
extern "C" void kernel_launch(void* const* d_in, const int* in_sizes, int n_in,
                              void* d_out, int out_size, void* d_ws, size_t ws_size,
                              hipStream_t stream)
{
    (void)in_sizes; (void)n_in; (void)out_size; (void)ws_size;

    const size_t S = 12845056;               // one [B,N,CI] bf16 slab (bytes)
    const size_t SE = S / 2;                 // slab element count
    char* base = (char*)d_ws;
    u16*   xT    = (u16*)(base);             // [0, 2S)   steps 1-2
    u16*   gT    = (u16*)(base);             // [0, S)    steps 3-4
    u16*   y     = (u16*)(base + S);         // [S, 2S)   steps 5-6 (= yp2)
    u16*   th    = (u16*)(base + 2 * S);     // [2S, 3S)  steps 2-4
    u16*   wy    = (u16*)(base + 2 * S);     // [2S, 4S)  steps 6-8
    u16*   gn    = (u16*)(base + 4 * S);     // [4S, 5S)  steps 2-3 (= yp3)
    float* lpart = (float*)(base + 5 * S);                          // 401 KB
    float* stats = (float*)(base + 5 * S + (size_t)4 * BN_ * 4);
    u16*   cw    = (u16*)(base + 5 * S + (size_t)4 * BN_ * 4 + 4096);
    int*   flag  = (int*)(base + 5 * S + (size_t)4 * BN_ * 4 + 4096 + 1055744);

    // canonical param layout: [tw|tb][pw|pb][gw|gb][ww|wb][gamma][beta]
    u16* ctw = cw;               u16* ctb = cw + 131072;
    u16* cww = ctb + 256 + 2 * 131328;  u16* cwb = cww + 131072;
    u16* cga = cwb + 512;        u16* cbe = cga + 512;

    u16* yp0 = (u16*)d_out;             // d_out = 2 slabs of scratch
    u16* yp1 = (u16*)d_out + SE;
    u16* yp2 = y;                       // combine reads then writes in place
    u16* yp3 = gn;                      // gn dead after transpose64

    detect_dtype<<<1, 256, 0, stream>>>((const u32*)d_in[0], flag, stats);
    convert_params<<<dim3(64, 10), 256, 0, stream>>>(
        d_in[1], d_in[2], d_in[3], d_in[4], d_in[5], d_in[6], d_in[7],
        d_in[8], d_in[9], d_in[10], cw, flag);

    transpose_x<<<dim3(N_ / 64, C_ / 64, B_), 256, 0, stream>>>(d_in[0], xT, flag);

    // fused theta/phi/g projections: z selects weight set + output slab
    gemm128<C_><<<dim3(BN_ / 128, CI_ / 128, 3), 256, 0, stream>>>(
        xT, ctw, ctb, th, CI_, 131328L, (long)SE);

    transpose64<<<dim3(CI_ / 64, N_ / 64, B_), 256, 0, stream>>>(gn, gT, N_, CI_);

    attn<<<dim3(25, B_, 4), 256, 0, stream>>>(
        th, th + SE, gT, yp0, yp1, yp2, yp3, lpart);

    attn_combine<<<dim3((BN_ * 32) / 256), 256, 0, stream>>>(
        yp0, yp1, yp2, yp3, lpart, y);

    // W GEMM: [25088,256] x [512,256]^T -> wy bf16 [25088,512]
    gemm128<CI_><<<dim3(BN_ / 128, C_ / 128, 1), 256, 0, stream>>>(
        y, cww, cwb, wy, C_, 0L, 0L);

    bn_stats<<<BN_ / 32, 256, 0, stream>>>(wy, stats);

    bn_apply<<<dim3(N_ / 64, C_ / 64, B_), 256, 0, stream>>>(
        wy, d_in[0], cga, cbe, stats, d_out, flag);
}

// Round 9
// 375.562 us; speedup vs baseline: 1.0307x; 1.0307x over previous
//
#include <hip/hip_runtime.h>
#include <hip/hip_bf16.h>

// NonLocalBlock: B=8, C=512, CI=256, H=W=56, N=3136.
// Round-9: fusion round. 6 dispatches:
//   1 convert_params (+flag inline, +stats zero)
//   2 transpose_x    (flag inline)
//   3 gemm_proj      (theta/phi row-major; g written TRANSPOSED -> gT)
//   4 attn           (identical to r8)
//   5 gemm_w         (A = combine(yp0..yp3)/l inline; bn partial sums fused)
//   6 bn_apply       (flag inline)
// transpose64 / attn_combine / bn_stats / detect_dtype deleted (~154 MB).

typedef unsigned short u16;
typedef unsigned int u32;
typedef __attribute__((ext_vector_type(8))) short short8;   // 8 bf16
typedef __attribute__((ext_vector_type(4))) float floatx4;

#define B_   8
#define C_   512
#define CI_  256
#define N_   3136
#define BN_  25088   // B_*N_

__device__ __forceinline__ u16 f2b(float f) {
    return __builtin_bit_cast(u16, __float2bfloat16(f));
}
__device__ __forceinline__ float b2f(u16 u) {
    return __bfloat162float(__builtin_bit_cast(__hip_bfloat16, u));
}
__device__ __forceinline__ floatx4 mfma16(short8 a, short8 b, floatx4 c) {
    return __builtin_amdgcn_mfma_f32_16x16x32_bf16(a, b, c, 0, 0, 0);
}
// async global->LDS DMA, 16 B/lane; LDS dest = wave-uniform base + lane*16,
// source address fully per-lane (gather).
__device__ __forceinline__ void gload_lds16(const u16* g, u16* l) {
    __builtin_amdgcn_global_load_lds(
        (const __attribute__((address_space(1))) u32*)g,
        (__attribute__((address_space(3))) u32*)l, 16, 0, 0);
}

// Per-block dtype flag from a 4KB x prefix (bf16-pair vs fp32 mantissa noise).
// Call at kernel top with all 256 threads active.
__device__ __forceinline__ int block_flag(const void* x) {
    __shared__ int cnt_;
    if (threadIdx.x == 0) cnt_ = 0;
    __syncthreads();
    const u32* xw = (const u32*)x;
    int c = 0;
#pragma unroll
    for (int i = 0; i < 4; ++i) {
        u32 w = xw[threadIdx.x * 4 + i];
        u32 e = (w >> 7) & 0xFF;
        c += (e >= 118 && e <= 130) ? 1 : 0;
    }
    atomicAdd(&cnt_, c);
    __syncthreads();
    return (2 * cnt_ > 1024) ? 1 : 0;
}

// ---------------------------------------------------------------------------
// Convert 10 parameter arrays into canonical bf16 (flag inline).
// Block (0,0) additionally zeroes the BN stats buffer.
// ---------------------------------------------------------------------------
__global__ __launch_bounds__(256) void convert_params(
    const void* __restrict__ x,
    const void* tw, const void* tb, const void* pw, const void* pb,
    const void* gw, const void* gbi, const void* ww, const void* wb,
    const void* gamma, const void* beta,
    u16* __restrict__ dst, float* __restrict__ stats)
{
    const int fl = block_flag(x);
    if (blockIdx.x == 0 && blockIdx.y == 0) {
        stats[threadIdx.x] = 0.f;
        stats[threadIdx.x + 256] = 0.f;
        stats[threadIdx.x + 512] = 0.f;
        stats[threadIdx.x + 768] = 0.f;
    }
    const void* srcs[10] = {tw, tb, pw, pb, gw, gbi, ww, wb, gamma, beta};
    const int ns[10] = {131072, 256, 131072, 256, 131072, 256, 131072, 512, 512, 512};
    int seg = blockIdx.y;
    int off = 0;
    for (int s = 0; s < 10; ++s) { if (s == seg) break; off += ns[s]; }
    const void* src = srcs[seg];
    int n = ns[seg];
    int i0 = (blockIdx.x * 256 + threadIdx.x) * 8;
    if (i0 >= n) return;
    u16* d = dst + off;
    for (int k = 0; k < 8; ++k) {
        int i = i0 + k;
        if (i < n)
            d[i] = fl ? ((const u16*)src)[i] : f2b(((const float*)src)[i]);
    }
}

// ---------------------------------------------------------------------------
// x ingest + transpose: x [b,C,N] (fp32 or bf16) -> xT [b,N,C] bf16.
// ---------------------------------------------------------------------------
__global__ __launch_bounds__(256) void transpose_x(
    const void* __restrict__ in, u16* __restrict__ out)
{
    const int fl = block_flag(in);
    __shared__ u16 tile[64][68];
    const int t = threadIdx.x;
    const long base = (long)blockIdx.z * (long)C_ * (long)N_;
    const int c0 = blockIdx.x * 64, r0 = blockIdx.y * 64;
    const int lr = t >> 3;
    const int lc = (t & 7) * 8;
#pragma unroll
    for (int j = 0; j < 2; ++j) {
        int rr = lr + 32 * j;
        long eoff = base + (long)(r0 + rr) * N_ + c0 + lc;
        u16 v[8] __attribute__((aligned(16)));
        if (fl) {
            const u16* pi = (const u16*)in + eoff;
            *(uint64_t*)&v[0] = *(const uint64_t*)pi;
            *(uint64_t*)&v[4] = *(const uint64_t*)(pi + 4);
        } else {
            const float* pi = (const float*)in + eoff;
            floatx4 a = *(const floatx4*)pi;
            floatx4 b4 = *(const floatx4*)(pi + 4);
#pragma unroll
            for (int k = 0; k < 4; ++k) { v[k] = f2b(a[k]); v[4 + k] = f2b(b4[k]); }
        }
        *(uint64_t*)&tile[rr][lc] = *(const uint64_t*)&v[0];
        *(uint64_t*)&tile[rr][lc + 4] = *(const uint64_t*)&v[4];
    }
    __syncthreads();
#pragma unroll
    for (int j = 0; j < 2; ++j) {
        int oc = lr + 32 * j;
        int ob = (t & 7) * 8;
        u16 vals[8] __attribute__((aligned(16)));
#pragma unroll
        for (int k = 0; k < 8; ++k) vals[k] = tile[ob + k][oc];
        u16* po = out + (long)blockIdx.z * N_ * C_ + (long)(c0 + oc) * C_ + r0 + ob;
        *(uint64_t*)po = *(const uint64_t*)vals;
        *(uint64_t*)(po + 4) = *(const uint64_t*)(vals + 4);
    }
}

// ---------------------------------------------------------------------------
// gemm_proj: Out = xT [BN,512] x W[z]^T [256,512] + bias[z].  128x128 tile.
// z=0 -> th, z=1 -> ph (row-major [BN][CI]); z=2 -> gT [B][CI][N] via an
// in-LDS transpose of the output tile (replaces the transpose64 pass).
// Fragment-order DMA staging, dbuf. grid = (196, 2, 3), block = 256.
// LDS: staging 32 KB aliased with transpose tile 33 KB -> smem[16896] u16.
// ---------------------------------------------------------------------------
__global__ __launch_bounds__(256, 3) void gemm_proj(
    const u16* __restrict__ A,        // xT [BN][C]
    const u16* __restrict__ BtBase,   // ctw (3 sets, stride 131328)
    u16* __restrict__ OutBase,        // th; ph = +ostride
    u16* __restrict__ gT,             // [B][CI][N]
    long ostride)
{
    __shared__ __attribute__((aligned(16))) u16 smem[16896];  // 33792 B
    const int t = threadIdx.x;
    const int wave = t >> 6, lane = t & 63;
    const int q = lane >> 4, lx = lane & 15;
    const int m0 = blockIdx.x * 128;
    const int n0 = blockIdx.y * 128;          // ci tile base
    const int zz = blockIdx.z;
    const u16* Bt = BtBase + (long)zz * 131328L;
    const u16* bias = Bt + 131072;

    auto As = [&](int buf, int rg) -> u16* { return smem + (buf * 8 + rg) * 512; };
    auto Bs = [&](int buf, int rg) -> u16* { return smem + 8192 + (buf * 8 + rg) * 512; };

    floatx4 zero4 = {0.f, 0.f, 0.f, 0.f};
    floatx4 acc[4][4];
#pragma unroll
    for (int i = 0; i < 4; ++i)
#pragma unroll
        for (int j = 0; j < 4; ++j) acc[i][j] = zero4;

    auto stage = [&](int buf, int k0) {
#pragma unroll
        for (int i = 0; i < 2; ++i) {
            int rg = wave * 2 + i;
            gload_lds16(A + (long)(m0 + rg * 16 + lx) * C_ + k0 + q * 8, As(buf, rg));
            gload_lds16(Bt + (long)(n0 + rg * 16 + lx) * C_ + k0 + q * 8, Bs(buf, rg));
        }
    };

    stage(0, 0);
    const int rg0 = (wave >> 1) * 4, cg0 = (wave & 1) * 4;
    for (int s = 0; s < C_ / 32; ++s) {
        const int buf = s & 1;
        __syncthreads();
        if (s + 1 < C_ / 32) stage(buf ^ 1, (s + 1) * 32);
        short8 af[4], bfr[4];
#pragma unroll
        for (int i = 0; i < 4; ++i)
            af[i] = *(const short8*)(As(buf, rg0 + i) + lane * 8);
#pragma unroll
        for (int j = 0; j < 4; ++j)
            bfr[j] = *(const short8*)(Bs(buf, cg0 + j) + lane * 8);
#pragma unroll
        for (int i = 0; i < 4; ++i)
#pragma unroll
            for (int j = 0; j < 4; ++j)
                acc[i][j] = mfma16(af[i], bfr[j], acc[i][j]);
    }

    // C/D layout: col=lane&15, row=(lane>>4)*4+reg  [m89/m91]
    const int wr = (wave >> 1) * 64, wc = (wave & 1) * 64;
    if (zz < 2) {
        u16* Out = OutBase + (long)zz * ostride;
#pragma unroll
        for (int j = 0; j < 4; ++j) {
            int col = n0 + wc + j * 16 + lx;
            float bv = b2f(bias[col]);
#pragma unroll
            for (int i = 0; i < 4; ++i)
#pragma unroll
                for (int r = 0; r < 4; ++r) {
                    int row = m0 + wr + i * 16 + q * 4 + r;
                    Out[(long)row * CI_ + col] = f2b(acc[i][j][r] + bv);
                }
        }
    } else {
        __syncthreads();   // all staging reads done before LDS reuse
        // phase 1: tile[ci_local][n_local], pitch 132
#pragma unroll
        for (int j = 0; j < 4; ++j) {
            int cl = wc + j * 16 + lx;
            float bv = b2f(bias[n0 + cl]);
#pragma unroll
            for (int i = 0; i < 4; ++i)
#pragma unroll
                for (int r = 0; r < 4; ++r)
                    smem[cl * 132 + wr + i * 16 + q * 4 + r] =
                        f2b(acc[i][j][r] + bv);
        }
        __syncthreads();
        // phase 2: coalesced 16-n runs to gT (N%16==0 -> no batch straddle)
#pragma unroll
        for (int p = 0; p < 4; ++p) {
            int cc = (t >> 3) + p * 32;
            int nn0 = (t & 7) * 16;
            u16 vals[16] __attribute__((aligned(16)));
#pragma unroll
            for (int k = 0; k < 16; ++k) vals[k] = smem[cc * 132 + nn0 + k];
            int m = m0 + nn0;
            int bb = m / N_;
            int nn = m - bb * N_;
            u16* dst = gT + ((long)bb * CI_ + (n0 + cc)) * N_ + nn;
            *(short8*)dst = *(const short8*)&vals[0];
            *(short8*)(dst + 8) = *(const short8*)&vals[8];
        }
    }
}

// ---------------------------------------------------------------------------
// Fused attention (identical to r8): z-split 4, fragment-order DMA tiles,
// ones-MFMA row sums. grid = (25, B, 4), block = 256.
// ---------------------------------------------------------------------------
__global__ __launch_bounds__(256, 2) void attn(
    const u16* __restrict__ theta,   // [B][N][CI]
    const u16* __restrict__ phi,     // [B][N][CI]
    const u16* __restrict__ gT,      // [B][CI][N]
    u16* __restrict__ yp0, u16* __restrict__ yp1,
    u16* __restrict__ yp2, u16* __restrict__ yp3,
    float* __restrict__ lpart)       // [4][B][N] row exp-sums
{
    __shared__ __attribute__((aligned(16))) u16 psf[2][8][2][64][8];
    __shared__ __attribute__((aligned(16))) u16 gsf[2][16][64][8];
    __shared__ __attribute__((aligned(16))) u16 Ps[4][32][40];

    const int t = threadIdx.x;
    const int wave = t >> 6, lane = t & 63;
    const int q = lane >> 4, lx = lane & 15;
    const int b = blockIdx.y;
    const int z = blockIdx.z;
    const int n0w = blockIdx.x * 128 + wave * 32;
    const bool valid = n0w < N_;
    const u16* thb = theta + (long)b * N_ * CI_;
    const u16* phb = phi + (long)b * N_ * CI_;
    const u16* gb = gT + (long)b * CI_ * N_;

    short8 tf[2][8];
#pragma unroll
    for (int h = 0; h < 2; ++h) {
        int trow = n0w + h * 16 + lx;
        if (trow >= N_) trow = N_ - 1;
#pragma unroll
        for (int kk = 0; kk < 8; ++kk)
            tf[h][kk] = *(const short8*)(thb + (long)trow * CI_ + kk * 32 + q * 8);
    }

    floatx4 zero4 = {0.f, 0.f, 0.f, 0.f};
    floatx4 yacc[2][16];
#pragma unroll
    for (int h = 0; h < 2; ++h)
#pragma unroll
        for (int i = 0; i < 16; ++i) yacc[h][i] = zero4;
    floatx4 lacc[2] = {zero4, zero4};
    const short8 ones = {0x3F80, 0x3F80, 0x3F80, 0x3F80,
                         0x3F80, 0x3F80, 0x3F80, 0x3F80};

    const int mbeg = z * 800;
    const int mend = (z == 3) ? N_ : mbeg + 800;

    auto stage = [&](int buf, int m0) {
#pragma unroll
        for (int i = 0; i < 2; ++i) {
            int kc = wave * 2 + i;
#pragma unroll
            for (int h = 0; h < 2; ++h)
                gload_lds16(phb + (long)(m0 + h * 16 + lx) * CI_ + kc * 32 + q * 8,
                            &psf[buf][kc][h][0][0]);
        }
#pragma unroll
        for (int j4 = 0; j4 < 4; ++j4) {
            int ct = wave * 4 + j4;
            gload_lds16(gb + (long)(ct * 16 + lx) * N_ + m0 + q * 8,
                        &gsf[buf][ct][0][0]);
        }
    };

    stage(0, mbeg);
    const int NSTEP = (mend - mbeg) / 32;    // 25 or 23
    for (int s = 0; s < NSTEP; ++s) {
        const int buf = s & 1;
        __syncthreads();
        if (s + 1 < NSTEP) stage(buf ^ 1, mbeg + (s + 1) * 32);

        floatx4 sacc[2][2];
        sacc[0][0] = zero4; sacc[0][1] = zero4;
        sacc[1][0] = zero4; sacc[1][1] = zero4;
#pragma unroll
        for (int kk = 0; kk < 8; ++kk) {
            short8 bf0 = *(const short8*)&psf[buf][kk][0][lane][0];
            short8 bf1 = *(const short8*)&psf[buf][kk][1][lane][0];
            sacc[0][0] = mfma16(tf[0][kk], bf0, sacc[0][0]);
            sacc[1][0] = mfma16(tf[1][kk], bf0, sacc[1][0]);
            sacc[0][1] = mfma16(tf[0][kk], bf1, sacc[0][1]);
            sacc[1][1] = mfma16(tf[1][kk], bf1, sacc[1][1]);
        }

#pragma unroll
        for (int h = 0; h < 2; ++h)
#pragma unroll
            for (int mh = 0; mh < 2; ++mh)
#pragma unroll
                for (int r = 0; r < 4; ++r) {
                    float e = __expf(fminf(sacc[h][mh][r], 60.f));
                    Ps[wave][h * 16 + q * 4 + r][mh * 16 + lx] = f2b(e);
                }
        short8 gpre[4];
#pragma unroll
        for (int j = 0; j < 4; ++j)
            gpre[j] = *(const short8*)&gsf[buf][j][lane][0];
        __builtin_amdgcn_wave_barrier();
        short8 pA0 = *(const short8*)&Ps[wave][lx][q * 8];
        short8 pA1 = *(const short8*)&Ps[wave][16 + lx][q * 8];
        __builtin_amdgcn_wave_barrier();

#pragma unroll
        for (int j = 0; j < 4; ++j) {
            yacc[0][j] = mfma16(pA0, gpre[j], yacc[0][j]);
            yacc[1][j] = mfma16(pA1, gpre[j], yacc[1][j]);
        }
#pragma unroll
        for (int ct = 4; ct < 16; ++ct) {
            short8 gf = *(const short8*)&gsf[buf][ct][lane][0];
            yacc[0][ct] = mfma16(pA0, gf, yacc[0][ct]);
            yacc[1][ct] = mfma16(pA1, gf, yacc[1][ct]);
        }
        lacc[0] = mfma16(pA0, ones, lacc[0]);
        lacc[1] = mfma16(pA1, ones, lacc[1]);
    }

    if (valid) {
        u16* ypz = (z == 0) ? yp0 : (z == 1) ? yp1 : (z == 2) ? yp2 : yp3;
        u16* yb = ypz + (long)b * N_ * CI_;
#pragma unroll
        for (int h = 0; h < 2; ++h)
#pragma unroll
            for (int ct = 0; ct < 16; ++ct)
#pragma unroll
                for (int r = 0; r < 4; ++r)
                    yb[(long)(n0w + h * 16 + q * 4 + r) * CI_ + ct * 16 + lx] =
                        f2b(yacc[h][ct][r]);
        if (lx == 0) {
#pragma unroll
            for (int h = 0; h < 2; ++h)
#pragma unroll
                for (int r = 0; r < 4; ++r)
                    lpart[(long)z * BN_ + (long)b * N_ + n0w + h * 16 + q * 4 + r] =
                        lacc[h][r];
        }
    }
}

// ---------------------------------------------------------------------------
// gemm_w: wy[m][c] = sum_k y[m][k]*Wt[c][k] + wb[c], where y is combined
// on the fly from 4 attn partials: y = (yp0+yp1+yp2+yp3)[m][k] / l[m].
// Also accumulates per-channel BN sums (stats) via shfl + atomics.
// grid = (196, 4), block = 256.
// ---------------------------------------------------------------------------
__global__ __launch_bounds__(256, 3) void gemm_w(
    const u16* __restrict__ yp0, const u16* __restrict__ yp1,
    const u16* __restrict__ yp2, const u16* __restrict__ yp3,
    const float* __restrict__ lpart,
    const u16* __restrict__ Bt,       // cww [512][256]
    const u16* __restrict__ bias,     // cwb [512]
    u16* __restrict__ wy,             // [BN][512]
    float* __restrict__ stats)
{
    __shared__ __attribute__((aligned(16))) u16 Asf[2][8][64][8];
    __shared__ __attribute__((aligned(16))) u16 Bsf[2][8][64][8];

    const int t = threadIdx.x;
    const int wave = t >> 6, lane = t & 63;
    const int q = lane >> 4, lx = lane & 15;
    const int m0 = blockIdx.x * 128;
    const int n0 = blockIdx.y * 128;

    float rl[2];
#pragma unroll
    for (int i = 0; i < 2; ++i) {
        int row = m0 + (wave * 2 + i) * 16 + lx;
        rl[i] = 1.0f / (lpart[row] + lpart[BN_ + row] +
                        lpart[2 * BN_ + row] + lpart[3 * BN_ + row]);
    }

    floatx4 zero4 = {0.f, 0.f, 0.f, 0.f};
    floatx4 acc[4][4];
#pragma unroll
    for (int i = 0; i < 4; ++i)
#pragma unroll
        for (int j = 0; j < 4; ++j) acc[i][j] = zero4;

    short8 va[2][4];
    auto loadA = [&](int k0) {
#pragma unroll
        for (int i = 0; i < 2; ++i) {
            long off = (long)(m0 + (wave * 2 + i) * 16 + lx) * CI_ + k0 + q * 8;
            va[i][0] = *(const short8*)(yp0 + off);
            va[i][1] = *(const short8*)(yp1 + off);
            va[i][2] = *(const short8*)(yp2 + off);
            va[i][3] = *(const short8*)(yp3 + off);
        }
    };
    auto writeA = [&](int buf) {
#pragma unroll
        for (int i = 0; i < 2; ++i) {
            u16 pk[8] __attribute__((aligned(16)));
#pragma unroll
            for (int e = 0; e < 8; ++e) {
                float v = (b2f(((const u16*)&va[i][0])[e]) +
                           b2f(((const u16*)&va[i][1])[e]) +
                           b2f(((const u16*)&va[i][2])[e]) +
                           b2f(((const u16*)&va[i][3])[e])) * rl[i];
                pk[e] = f2b(v);
            }
            *(short8*)&Asf[buf][wave * 2 + i][lane][0] = *(const short8*)pk;
        }
    };
    auto stageB = [&](int buf, int k0) {
#pragma unroll
        for (int i = 0; i < 2; ++i) {
            int rg = wave * 2 + i;
            gload_lds16(Bt + (long)(n0 + rg * 16 + lx) * CI_ + k0 + q * 8,
                        &Bsf[buf][rg][0][0]);
        }
    };

    loadA(0); writeA(0); stageB(0, 0);
    const int rg0 = (wave >> 1) * 4, cg0 = (wave & 1) * 4;
    const int NS = CI_ / 32;   // 8
    for (int s = 0; s < NS; ++s) {
        const int buf = s & 1;
        __syncthreads();
        if (s + 1 < NS) { loadA((s + 1) * 32); stageB(buf ^ 1, (s + 1) * 32); }
        short8 af[4], bfr[4];
#pragma unroll
        for (int i = 0; i < 4; ++i)
            af[i] = *(const short8*)&Asf[buf][rg0 + i][lane][0];
#pragma unroll
        for (int j = 0; j < 4; ++j)
            bfr[j] = *(const short8*)&Bsf[buf][cg0 + j][lane][0];
#pragma unroll
        for (int i = 0; i < 4; ++i)
#pragma unroll
            for (int j = 0; j < 4; ++j)
                acc[i][j] = mfma16(af[i], bfr[j], acc[i][j]);
        if (s + 1 < NS) writeA(buf ^ 1);
    }

    // epilogue: bias, wy write, fused BN channel partials
    const int wr = (wave >> 1) * 64, wc = (wave & 1) * 64;
#pragma unroll
    for (int j = 0; j < 4; ++j) {
        int col = n0 + wc + j * 16 + lx;
        float bv = b2f(bias[col]);
        float cs = 0.f, cq = 0.f;
#pragma unroll
        for (int i = 0; i < 4; ++i)
#pragma unroll
            for (int r = 0; r < 4; ++r) {
                int row = m0 + wr + i * 16 + q * 4 + r;
                float v = acc[i][j][r] + bv;
                wy[(long)row * C_ + col] = f2b(v);
                cs += v; cq += v * v;
            }
        cs += __shfl_xor(cs, 16); cs += __shfl_xor(cs, 32);
        cq += __shfl_xor(cq, 16); cq += __shfl_xor(cq, 32);
        if (q == 0) {
            atomicAdd(&stats[col], cs);
            atomicAdd(&stats[C_ + col], cq);
        }
    }
}

// ---------------------------------------------------------------------------
// out[b][c][n] = (wy[b][n][c]-mean)*rstd*gamma + beta + x[b][c][n]
// ---------------------------------------------------------------------------
__global__ __launch_bounds__(256) void bn_apply(
    const u16* __restrict__ wy, const void* __restrict__ xv,
    const u16* __restrict__ gamma, const u16* __restrict__ beta,
    const float* __restrict__ stats, void* __restrict__ outv)
{
    const int fl = block_flag(xv);
    __shared__ float tile[64][65];
    const int t = threadIdx.x;
    const int nb0 = blockIdx.x * 64;
    const int c0 = blockIdx.y * 64;
    const int b = blockIdx.z;
#pragma unroll
    for (int j = 0; j < 4; ++j) {
        int row = (t >> 4) + 16 * j;
        int col = (t & 15) * 4;
        const u16* p = wy + ((long)b * N_ + nb0 + row) * C_ + c0 + col;
        u16 lv[4] __attribute__((aligned(8)));
        *(uint64_t*)lv = *(const uint64_t*)p;
#pragma unroll
        for (int k = 0; k < 4; ++k) tile[row][col + k] = b2f(lv[k]);
    }
    __syncthreads();
    const float inv = 1.0f / (float)BN_;
#pragma unroll
    for (int it = 0; it < 8; ++it) {
        int oc = (t >> 5) + 8 * it;
        int on = (t & 31) * 2;
        int c = c0 + oc;
        float mean = stats[c] * inv;
        float var = stats[C_ + c] * inv - mean * mean;
        float rstd = rsqrtf(var + 1e-5f);
        float sc = b2f(gamma[c]) * rstd;
        float sh = b2f(beta[c]) - mean * sc;
        long base = ((long)b * C_ + c) * N_ + nb0 + on;
        float v0 = tile[on][oc] * sc + sh;
        float v1 = tile[on + 1][oc] * sc + sh;
        if (fl) {
            v0 += b2f(((const u16*)xv)[base]);
            v1 += b2f(((const u16*)xv)[base + 1]);
            ((u16*)outv)[base] = f2b(v0);
            ((u16*)outv)[base + 1] = f2b(v1);
        } else {
            v0 += ((const float*)xv)[base];
            v1 += ((const float*)xv)[base + 1];
            ((float*)outv)[base] = v0;
            ((float*)outv)[base + 1] = v1;
        }
    }
}

// ---------------------------------------------------------------------------
extern "C" void kernel_launch(void* const* d_in, const int* in_sizes, int n_in,
                              void* d_out, int out_size, void* d_ws, size_t ws_size,
                              hipStream_t stream)
{
    (void)in_sizes; (void)n_in; (void)out_size; (void)ws_size;

    const size_t S = 12845056;               // one [B,N,CI] bf16 slab (bytes)
    const size_t SE = S / 2;                 // slab element count
    char* base = (char*)d_ws;
    u16*   xT    = (u16*)(base);             // [0, 2S)  convert->proj
    u16*   yp3   = (u16*)(base);             // [0, S)   attn->gemm_w
    u16*   yp2   = (u16*)(base + S);         // [S, 2S)  attn->gemm_w
    u16*   th    = (u16*)(base + 2 * S);     // [2S, 3S) proj->attn (ph=+SE)
    u16*   wy    = (u16*)(base + 2 * S);     // [2S, 4S) gemm_w->bn_apply
    u16*   gT    = (u16*)(base + 4 * S);     // [4S, 5S) proj->attn
    float* lpart = (float*)(base + 5 * S);                          // 401 KB
    float* stats = (float*)(base + 5 * S + (size_t)4 * BN_ * 4);
    u16*   cw    = (u16*)(base + 5 * S + (size_t)4 * BN_ * 4 + 4096);

    // canonical param offsets (convert_params segment order)
    u16* ctw = cw;
    u16* cww = cw + 393984;
    u16* cwb = cw + 525056;
    u16* cga = cw + 525568;
    u16* cbe = cw + 526080;

    u16* yp0 = (u16*)d_out;             // d_out = 2 slabs of scratch
    u16* yp1 = (u16*)d_out + SE;        // dead before bn_apply overwrites

    convert_params<<<dim3(64, 10), 256, 0, stream>>>(
        d_in[0], d_in[1], d_in[2], d_in[3], d_in[4], d_in[5], d_in[6],
        d_in[7], d_in[8], d_in[9], d_in[10], cw, stats);

    transpose_x<<<dim3(N_ / 64, C_ / 64, B_), 256, 0, stream>>>(d_in[0], xT);

    // fused theta/phi/g projections; g emitted transposed into gT
    gemm_proj<<<dim3(BN_ / 128, CI_ / 128, 3), 256, 0, stream>>>(
        xT, ctw, th, gT, (long)SE);

    attn<<<dim3(25, B_, 4), 256, 0, stream>>>(
        th, th + SE, gT, yp0, yp1, yp2, yp3, lpart);

    // W GEMM with inline softmax-combine + fused BN stats
    gemm_w<<<dim3(BN_ / 128, C_ / 128), 256, 0, stream>>>(
        yp0, yp1, yp2, yp3, lpart, cww, cwb, wy, stats);

    bn_apply<<<dim3(N_ / 64, C_ / 64, B_), 256, 0, stream>>>(
        wy, d_in[0], cga, cbe, stats, d_out);
}